// Round 1
// baseline (471.015 us; speedup 1.0000x reference)
//
#include <hip/hip_runtime.h>
#include <math.h>

typedef unsigned short u16;
typedef __attribute__((ext_vector_type(8))) short short8;
typedef __attribute__((ext_vector_type(8))) __bf16 bf16x8;
typedef __attribute__((ext_vector_type(4))) float floatx4;
typedef __attribute__((ext_vector_type(4))) unsigned short u16x4;
typedef __attribute__((ext_vector_type(4))) float float4v;

static __device__ __forceinline__ float b2f(u16 u) {
  unsigned int x = ((unsigned int)u) << 16;
  return __builtin_bit_cast(float, x);
}
static __device__ __forceinline__ u16 f2b(float f) {
  unsigned int x = __builtin_bit_cast(unsigned int, f);
  x += 0x7fffu + ((x >> 16) & 1u);
  return (u16)(x >> 16);
}
static __device__ __forceinline__ void gload_lds16(const void* g, void* l) {
  __builtin_amdgcn_global_load_lds(
      (const __attribute__((address_space(1))) unsigned int*)g,
      (__attribute__((address_space(3))) unsigned int*)l, 16, 0, 0);
}

// ---------- fp32 -> bf16 convert, vectorized x4 ----------
__global__ __launch_bounds__(256) void cvt_kernel(const float* __restrict__ in,
                                                  u16* __restrict__ out, int n4) {
  int i = blockIdx.x * 256 + threadIdx.x;
  if (i >= n4) return;
  float4v v = reinterpret_cast<const float4v*>(in)[i];
  u16x4 o;
  o[0] = f2b(v[0]); o[1] = f2b(v[1]); o[2] = f2b(v[2]); o[3] = f2b(v[3]);
  reinterpret_cast<u16x4*>(out)[i] = o;
}

// ---------- RoPE cos/sin tables: [S=2048][64] fp32 ----------
__global__ __launch_bounds__(256) void rope_table_kernel(float* __restrict__ ct,
                                                         float* __restrict__ st) {
  int idx = blockIdx.x * 256 + threadIdx.x;  // S*64 = 131072
  int s = idx >> 6, j = idx & 63;
  float inv = powf(10000.0f, -(float)j * (1.0f / 64.0f));
  float ang = (float)s * inv;
  ct[idx] = cosf(ang);
  st[idx] = sinf(ang);
}

// ---------- RoPE + layout: [B*S][nh*128] -> [B][nh][S][128] ----------
__global__ __launch_bounds__(256) void rope_kernel(const u16* __restrict__ in,
                                                   u16* __restrict__ out,
                                                   const float* __restrict__ ct,
                                                   const float* __restrict__ st, int nh) {
  int idx = blockIdx.x * 256 + threadIdx.x;  // B*S*nh*64
  int j = idx & 63;
  int rest = idx >> 6;
  int h = rest % nh;
  int bs = rest / nh;  // b*2048 + s
  int s = bs & 2047;
  int b = bs >> 11;
  size_t inoff = (size_t)bs * (nh * 128) + h * 128 + j;
  float t1 = b2f(in[inoff]);
  float t2 = b2f(in[inoff + 64]);
  float c = ct[s * 64 + j], sn = st[s * 64 + j];
  size_t ooff = ((size_t)(b * nh + h) * 2048 + s) * 128 + j;
  out[ooff] = f2b(t1 * c - t2 * sn);
  out[ooff + 64] = f2b(t2 * c + t1 * sn);
}

// ---------- V transpose: [B*S][KV*128] -> [B][KV][128][S] ----------
__global__ __launch_bounds__(256) void vtrans_kernel(const u16* __restrict__ in,
                                                     u16* __restrict__ out) {
  __shared__ u16 t[128][66];
  int s0 = blockIdx.x * 64;
  int b = blockIdx.y >> 2, kv = blockIdx.y & 3;
  int tid = threadIdx.x;
#pragma unroll
  for (int it = 0; it < 32; ++it) {
    int idx = it * 256 + tid;
    int sl = idx >> 7, d = idx & 127;
    t[d][sl] = in[(size_t)(b * 2048 + s0 + sl) * 512 + kv * 128 + d];
  }
  __syncthreads();
#pragma unroll
  for (int it = 0; it < 32; ++it) {
    int idx = it * 256 + tid;
    int d = idx >> 6, sl = idx & 63;
    out[(size_t)((b * 4 + kv) * 128 + d) * 2048 + s0 + sl] = t[d][sl];
  }
}

// ---------- bf16 GEMM: C[M][N] = A[M][K] * B[N][K]^T (m97-style 128x128 tile) ----------
static __device__ __forceinline__ void store_out(u16* p, float v) { *p = f2b(v); }
static __device__ __forceinline__ void store_out(float* p, float v) { *p = v; }

template <typename OutT>
__global__ __launch_bounds__(256) void gemm_bt(const u16* __restrict__ A,
                                               const u16* __restrict__ B,
                                               OutT* __restrict__ C, int M, int N, int K) {
  __shared__ __align__(16) u16 Al[128 * 32];
  __shared__ __align__(16) u16 Bl[128 * 32];
  const int tid = threadIdx.x;
  const int lane = tid & 63;
  const int w = tid >> 6;
  const int wr = w >> 1, wc = w & 1;
  const int lr = lane & 15, lg = lane >> 4;
  const int brow = blockIdx.y, bcol = blockIdx.x;
  const int r0 = lane >> 2, kp = lane & 3;
  const u16* Ag = A + (size_t)(brow * 128) * K;
  const u16* Bg = B + (size_t)(bcol * 128) * K;
  floatx4 acc[4][4] = {};
  for (int k0 = 0; k0 < K; k0 += 32) {
#pragma unroll
    for (int j = 0; j < 2; ++j) {
      int c = w * 2 + j;
      int row = c * 16 + r0;
      gload_lds16(Ag + (size_t)row * K + k0 + kp * 8, &Al[c * 512]);
      gload_lds16(Bg + (size_t)row * K + k0 + kp * 8, &Bl[c * 512]);
    }
    __syncthreads();
    bf16x8 af[4], bfr[4];
#pragma unroll
    for (int m = 0; m < 4; ++m)
      af[m] = *reinterpret_cast<const bf16x8*>(&Al[(wr * 64 + m * 16 + lr) * 32 + lg * 8]);
#pragma unroll
    for (int n = 0; n < 4; ++n)
      bfr[n] = *reinterpret_cast<const bf16x8*>(&Bl[(wc * 64 + n * 16 + lr) * 32 + lg * 8]);
#pragma unroll
    for (int m = 0; m < 4; ++m)
#pragma unroll
      for (int n = 0; n < 4; ++n)
        acc[m][n] = __builtin_amdgcn_mfma_f32_16x16x32_bf16(af[m], bfr[n], acc[m][n], 0, 0, 0);
    __syncthreads();
  }
#pragma unroll
  for (int m = 0; m < 4; ++m) {
    int row = brow * 128 + wr * 64 + m * 16 + lg * 4;
#pragma unroll
    for (int n = 0; n < 4; ++n) {
      int col = bcol * 128 + wc * 64 + n * 16 + lr;
#pragma unroll
      for (int i = 0; i < 4; ++i) store_out(&C[(size_t)(row + i) * N + col], acc[m][n][i]);
    }
  }
}

// ---------- causal GQA flash attention ----------
// Q: [B][16][S][128], K: [B][4][S][128], V (transposed): [B][4][128][S]
// O: [B][S][2048] bf16.  Block: 4 waves, 64 q-rows; wave owns 16 q-rows.
__global__ __launch_bounds__(256) void attn_kernel(const u16* __restrict__ Q,
                                                   const u16* __restrict__ K,
                                                   const u16* __restrict__ V,
                                                   u16* __restrict__ O) {
  __shared__ __align__(16) u16 Kl[32 * 136];   // [32 keys][128 d] pad->136
  __shared__ __align__(16) u16 Vl[128 * 40];   // [128 d][32 keys] pad->40
  __shared__ __align__(16) u16 Pl[4 * 16 * 40];  // per-wave P [16 q][32 k] pad->40
  const int tid = threadIdx.x, lane = tid & 63, w = tid >> 6;
  const int lr = lane & 15, lg = lane >> 4;
  const int q0 = blockIdx.x * 64;
  const int b = blockIdx.y >> 4, h = blockIdx.y & 15, kv = h >> 2;
  const u16* Qp = Q + (size_t)(b * 16 + h) * 2048 * 128;
  const u16* Kp = K + (size_t)(b * 4 + kv) * 2048 * 128;
  const u16* Vp = V + (size_t)(b * 4 + kv) * 128 * 2048;
  const int qbase = q0 + w * 16;
  bf16x8 aq[4];
#pragma unroll
  for (int dc = 0; dc < 4; ++dc)
    aq[dc] = *reinterpret_cast<const bf16x8*>(Qp + (size_t)(qbase + lr) * 128 + dc * 32 + lg * 8);
  float m_r[4], l_r[4];
  floatx4 oa[8] = {};
#pragma unroll
  for (int i = 0; i < 4; ++i) { m_r[i] = -3.0e38f; l_r[i] = 0.0f; }
  const int nkb = (q0 + 64) >> 5;
  const float scale = 0.08838834764831845f;  // 1/sqrt(128)
  for (int kb = 0; kb < nkb; ++kb) {
    // stage K tile [32][128] and Vt tile [128][32]
#pragma unroll
    for (int j = 0; j < 2; ++j) {
      int u = tid + j * 256;
      int krow = u >> 4, dpart = u & 15;
      short8 kreg = *reinterpret_cast<const short8*>(Kp + (size_t)(kb * 32 + krow) * 128 + dpart * 8);
      *reinterpret_cast<short8*>(&Kl[krow * 136 + dpart * 8]) = kreg;
      int d = u >> 2, kpart = u & 3;
      short8 vreg = *reinterpret_cast<const short8*>(Vp + (size_t)d * 2048 + kb * 32 + kpart * 8);
      *reinterpret_cast<short8*>(&Vl[d * 40 + kpart * 8]) = vreg;
    }
    __syncthreads();
    // S = Q K^T for 32 keys: two 16-col fragments
    floatx4 s0 = {}, s1 = {};
#pragma unroll
    for (int dc = 0; dc < 4; ++dc) {
      bf16x8 b0 = *reinterpret_cast<const bf16x8*>(&Kl[lr * 136 + dc * 32 + lg * 8]);
      bf16x8 b1 = *reinterpret_cast<const bf16x8*>(&Kl[(16 + lr) * 136 + dc * 32 + lg * 8]);
      s0 = __builtin_amdgcn_mfma_f32_16x16x32_bf16(aq[dc], b0, s0, 0, 0, 0);
      s1 = __builtin_amdgcn_mfma_f32_16x16x32_bf16(aq[dc], b1, s1, 0, 0, 0);
    }
    // online softmax per q-row (4 rows per lane, reduce across 16-lane key groups)
#pragma unroll
    for (int i = 0; i < 4; ++i) {
      int qg = qbase + lg * 4 + i;
      int kg = kb * 32 + lr;
      float v0 = (kg <= qg) ? s0[i] * scale : -3.0e38f;
      float v1 = (kg + 16 <= qg) ? s1[i] * scale : -3.0e38f;
      float tm = fmaxf(v0, v1);
      tm = fmaxf(tm, __shfl_xor(tm, 1));
      tm = fmaxf(tm, __shfl_xor(tm, 2));
      tm = fmaxf(tm, __shfl_xor(tm, 4));
      tm = fmaxf(tm, __shfl_xor(tm, 8));
      float mn = fmaxf(m_r[i], tm);
      float p0 = __expf(v0 - mn), p1 = __expf(v1 - mn);
      float alpha = __expf(m_r[i] - mn);
      float ts = p0 + p1;
      ts += __shfl_xor(ts, 1);
      ts += __shfl_xor(ts, 2);
      ts += __shfl_xor(ts, 4);
      ts += __shfl_xor(ts, 8);
      l_r[i] = l_r[i] * alpha + ts;
      m_r[i] = mn;
#pragma unroll
      for (int t = 0; t < 8; ++t) oa[t][i] *= alpha;
      Pl[w * 640 + (lg * 4 + i) * 40 + lr] = f2b(p0);
      Pl[w * 640 + (lg * 4 + i) * 40 + lr + 16] = f2b(p1);
    }
    // wave-local LDS RAW fence (P written by all lanes of this wave, re-read below)
    asm volatile("s_waitcnt lgkmcnt(0)" ::: "memory");
    // O += P V  (A = P [16q x 32k], B = V [32k x 16d] from Vt rows)
    bf16x8 ap = *reinterpret_cast<const bf16x8*>(&Pl[w * 640 + lr * 40 + lg * 8]);
#pragma unroll
    for (int t = 0; t < 8; ++t) {
      bf16x8 bv = *reinterpret_cast<const bf16x8*>(&Vl[(t * 16 + lr) * 40 + lg * 8]);
      oa[t] = __builtin_amdgcn_mfma_f32_16x16x32_bf16(ap, bv, oa[t], 0, 0, 0);
    }
    __syncthreads();
  }
#pragma unroll
  for (int i = 0; i < 4; ++i) {
    int s = qbase + lg * 4 + i;
    float inv = 1.0f / l_r[i];
#pragma unroll
    for (int t = 0; t < 8; ++t)
      O[((size_t)b * 2048 + s) * 2048 + h * 128 + t * 16 + lr] = f2b(oa[t][i] * inv);
  }
}

extern "C" void kernel_launch(void* const* d_in, const int* in_sizes, int n_in,
                              void* d_out, int out_size, void* d_ws, size_t ws_size,
                              hipStream_t stream) {
  const float* x  = (const float*)d_in[0];
  const float* wq = (const float*)d_in[1];
  const float* wk = (const float*)d_in[2];
  const float* wv = (const float*)d_in[3];
  const float* wo = (const float*)d_in[4];
  float* out = (float*)d_out;
  char* ws = (char*)d_ws;
  size_t off = 0;
  auto alloc = [&](size_t bytes) -> void* {
    void* p = ws + off;
    off = (off + bytes + 255) & ~(size_t)255;
    return p;
  };
  u16* xb   = (u16*)alloc(4096ull * 2048 * 2);  // x bf16; later reused as q_rope
  u16* wqb  = (u16*)alloc(2048ull * 2048 * 2);
  u16* wkb  = (u16*)alloc(512ull * 2048 * 2);
  u16* wvb  = (u16*)alloc(512ull * 2048 * 2);
  u16* wob  = (u16*)alloc(2048ull * 2048 * 2);
  u16* qlin = (u16*)alloc(4096ull * 2048 * 2);  // later reused as attn output
  u16* klin = (u16*)alloc(4096ull * 512 * 2);
  u16* vlin = (u16*)alloc(4096ull * 512 * 2);
  u16* kr   = (u16*)alloc(4096ull * 512 * 2);
  u16* vtb  = (u16*)alloc(4096ull * 512 * 2);
  float* ctab = (float*)alloc(2048ull * 64 * 4);
  float* stab = (float*)alloc(2048ull * 64 * 4);
  u16* qr    = xb;    // safe: all projections read xb before rope_q runs
  u16* attnb = qlin;  // safe: qlin last read by rope_q, before attn runs
  (void)in_sizes; (void)n_in; (void)out_size; (void)ws_size;

  cvt_kernel<<<8192, 256, 0, stream>>>(x, xb, 2097152);
  cvt_kernel<<<4096, 256, 0, stream>>>(wq, wqb, 1048576);
  cvt_kernel<<<1024, 256, 0, stream>>>(wk, wkb, 262144);
  cvt_kernel<<<1024, 256, 0, stream>>>(wv, wvb, 262144);
  cvt_kernel<<<4096, 256, 0, stream>>>(wo, wob, 1048576);
  rope_table_kernel<<<512, 256, 0, stream>>>(ctab, stab);

  gemm_bt<u16><<<dim3(16, 32), 256, 0, stream>>>(xb, wqb, qlin, 4096, 2048, 2048);
  gemm_bt<u16><<<dim3(4, 32), 256, 0, stream>>>(xb, wkb, klin, 4096, 512, 2048);
  gemm_bt<u16><<<dim3(4, 32), 256, 0, stream>>>(xb, wvb, vlin, 4096, 512, 2048);

  rope_kernel<<<16384, 256, 0, stream>>>(qlin, qr, ctab, stab, 16);
  rope_kernel<<<4096, 256, 0, stream>>>(klin, kr, ctab, stab, 4);
  vtrans_kernel<<<dim3(32, 8), 256, 0, stream>>>(vlin, vtb);

  attn_kernel<<<dim3(32, 32), 256, 0, stream>>>(qr, kr, vtb, attnb);

  gemm_bt<float><<<dim3(16, 32), 256, 0, stream>>>(attnb, wob, out, 4096, 2048, 2048);
}

// Round 2
// 370.490 us; speedup vs baseline: 1.2713x; 1.2713x over previous
//
#include <hip/hip_runtime.h>
#include <math.h>

typedef unsigned short u16;
typedef __attribute__((ext_vector_type(8))) short short8;
typedef __attribute__((ext_vector_type(8))) __bf16 bf16x8;
typedef __attribute__((ext_vector_type(4))) float floatx4;
typedef __attribute__((ext_vector_type(4))) unsigned short u16x4;
typedef __attribute__((ext_vector_type(4))) float float4v;

static __device__ __forceinline__ float b2f(u16 u) {
  unsigned int x = ((unsigned int)u) << 16;
  return __builtin_bit_cast(float, x);
}
static __device__ __forceinline__ u16 f2b(float f) {
  unsigned int x = __builtin_bit_cast(unsigned int, f);
  x += 0x7fffu + ((x >> 16) & 1u);
  return (u16)(x >> 16);
}
static __device__ __forceinline__ void gload_lds16(const void* g, void* l) {
  __builtin_amdgcn_global_load_lds(
      (const __attribute__((address_space(1))) unsigned int*)g,
      (__attribute__((address_space(3))) unsigned int*)l, 16, 0, 0);
}

// ---------- fp32 -> bf16 convert, vectorized x4 ----------
__global__ __launch_bounds__(256) void cvt_kernel(const float* __restrict__ in,
                                                  u16* __restrict__ out, int n4) {
  int i = blockIdx.x * 256 + threadIdx.x;
  if (i >= n4) return;
  float4v v = reinterpret_cast<const float4v*>(in)[i];
  u16x4 o;
  o[0] = f2b(v[0]); o[1] = f2b(v[1]); o[2] = f2b(v[2]); o[3] = f2b(v[3]);
  reinterpret_cast<u16x4*>(out)[i] = o;
}

// ---------- RoPE cos/sin tables: [S=2048][64] fp32 ----------
__global__ __launch_bounds__(256) void rope_table_kernel(float* __restrict__ ct,
                                                         float* __restrict__ st) {
  int idx = blockIdx.x * 256 + threadIdx.x;  // S*64 = 131072
  int s = idx >> 6, j = idx & 63;
  float inv = powf(10000.0f, -(float)j * (1.0f / 64.0f));
  float ang = (float)s * inv;
  ct[idx] = cosf(ang);
  st[idx] = sinf(ang);
}

// ---------- RoPE + layout: [B*S][nh*128] -> [B][nh][S][128], 8 j per thread ----------
__global__ __launch_bounds__(256) void rope_kernel(const u16* __restrict__ in,
                                                   u16* __restrict__ out,
                                                   const float* __restrict__ ct,
                                                   const float* __restrict__ st, int nh) {
  int idx = blockIdx.x * 256 + threadIdx.x;  // B*S*nh*8
  int jc = idx & 7;
  int rest = idx >> 3;
  int h = rest % nh;
  int bs = rest / nh;  // b*2048 + s
  int s = bs & 2047;
  int b = bs >> 11;
  int j0 = jc * 8;
  size_t inoff = (size_t)bs * (nh * 128) + h * 128 + j0;
  short8 lo = *reinterpret_cast<const short8*>(&in[inoff]);
  short8 hi = *reinterpret_cast<const short8*>(&in[inoff + 64]);
  float4v c0 = *reinterpret_cast<const float4v*>(&ct[s * 64 + j0]);
  float4v c1 = *reinterpret_cast<const float4v*>(&ct[s * 64 + j0 + 4]);
  float4v sn0 = *reinterpret_cast<const float4v*>(&st[s * 64 + j0]);
  float4v sn1 = *reinterpret_cast<const float4v*>(&st[s * 64 + j0 + 4]);
  short8 o0, o1;
#pragma unroll
  for (int e = 0; e < 8; ++e) {
    float c = (e < 4) ? c0[e & 3] : c1[e & 3];
    float sn = (e < 4) ? sn0[e & 3] : sn1[e & 3];
    float t1 = b2f((u16)lo[e]);
    float t2 = b2f((u16)hi[e]);
    o0[e] = (short)f2b(t1 * c - t2 * sn);
    o1[e] = (short)f2b(t2 * c + t1 * sn);
  }
  size_t ooff = ((size_t)(b * nh + h) * 2048 + s) * 128 + j0;
  *reinterpret_cast<short8*>(&out[ooff]) = o0;
  *reinterpret_cast<short8*>(&out[ooff + 64]) = o1;
}

// ---------- V transpose: [B*S][KV*128] -> [B][KV][128][S] ----------
__global__ __launch_bounds__(256) void vtrans_kernel(const u16* __restrict__ in,
                                                     u16* __restrict__ out) {
  __shared__ u16 t[128][66];
  int s0 = blockIdx.x * 64;
  int b = blockIdx.y >> 2, kv = blockIdx.y & 3;
  int tid = threadIdx.x;
#pragma unroll
  for (int it = 0; it < 32; ++it) {
    int idx = it * 256 + tid;
    int sl = idx >> 7, d = idx & 127;
    t[d][sl] = in[(size_t)(b * 2048 + s0 + sl) * 512 + kv * 128 + d];
  }
  __syncthreads();
#pragma unroll
  for (int it = 0; it < 32; ++it) {
    int idx = it * 256 + tid;
    int d = idx >> 6, sl = idx & 63;
    out[(size_t)((b * 4 + kv) * 128 + d) * 2048 + s0 + sl] = t[d][sl];
  }
}

// ---------- bf16 GEMM: C[M][N] = A[M][K] * B[N][K]^T (m97-style 128x128 tile) ----------
static __device__ __forceinline__ void store_out(u16* p, float v) { *p = f2b(v); }
static __device__ __forceinline__ void store_out(float* p, float v) { *p = v; }

template <typename OutT>
__global__ __launch_bounds__(256) void gemm_bt(const u16* __restrict__ A,
                                               const u16* __restrict__ B,
                                               OutT* __restrict__ C, int M, int N, int K) {
  __shared__ __align__(16) u16 Al[128 * 32];
  __shared__ __align__(16) u16 Bl[128 * 32];
  const int tid = threadIdx.x;
  const int lane = tid & 63;
  const int w = tid >> 6;
  const int wr = w >> 1, wc = w & 1;
  const int lr = lane & 15, lg = lane >> 4;
  const int brow = blockIdx.y, bcol = blockIdx.x;
  const int r0 = lane >> 2, kp = lane & 3;
  const u16* Ag = A + (size_t)(brow * 128) * K;
  const u16* Bg = B + (size_t)(bcol * 128) * K;
  floatx4 acc[4][4] = {};
  for (int k0 = 0; k0 < K; k0 += 32) {
#pragma unroll
    for (int j = 0; j < 2; ++j) {
      int c = w * 2 + j;
      int row = c * 16 + r0;
      gload_lds16(Ag + (size_t)row * K + k0 + kp * 8, &Al[c * 512]);
      gload_lds16(Bg + (size_t)row * K + k0 + kp * 8, &Bl[c * 512]);
    }
    __syncthreads();
    bf16x8 af[4], bfr[4];
#pragma unroll
    for (int m = 0; m < 4; ++m)
      af[m] = *reinterpret_cast<const bf16x8*>(&Al[(wr * 64 + m * 16 + lr) * 32 + lg * 8]);
#pragma unroll
    for (int n = 0; n < 4; ++n)
      bfr[n] = *reinterpret_cast<const bf16x8*>(&Bl[(wc * 64 + n * 16 + lr) * 32 + lg * 8]);
#pragma unroll
    for (int m = 0; m < 4; ++m)
#pragma unroll
      for (int n = 0; n < 4; ++n)
        acc[m][n] = __builtin_amdgcn_mfma_f32_16x16x32_bf16(af[m], bfr[n], acc[m][n], 0, 0, 0);
    __syncthreads();
  }
#pragma unroll
  for (int m = 0; m < 4; ++m) {
    int row = brow * 128 + wr * 64 + m * 16 + lg * 4;
#pragma unroll
    for (int n = 0; n < 4; ++n) {
      int col = bcol * 128 + wc * 64 + n * 16 + lr;
#pragma unroll
      for (int i = 0; i < 4; ++i) store_out(&C[(size_t)(row + i) * N + col], acc[m][n][i]);
    }
  }
}

// ---------- causal GQA flash attention, v2 ----------
// Paired q-tiles (pi, 31-pi): uniform 33 KV-tiles of compute per block.
// KVBLK=64 staged once per kb, serves both q-tiles. XOR-swizzled LDS
// (both-sides: pre-swizzled global src for global_load_lds + swizzled reads).
static __device__ __forceinline__ void attn_tile(
    const bf16x8 (&aq)[4], floatx4 (&oa)[8], float (&m_r)[4], float (&l_r)[4],
    u16* __restrict__ Plw, const u16* __restrict__ Kl, const u16* __restrict__ Vl,
    int qbase, int kb, bool diag, int lr, int lg) {
  const float scale = 0.08838834764831845f;
  floatx4 s[4] = {};
#pragma unroll
  for (int dc = 0; dc < 4; ++dc) {
#pragma unroll
    for (int kc = 0; kc < 4; ++kc) {
      int row = kc * 16 + lr;
      bf16x8 bk = *reinterpret_cast<const bf16x8*>(
          &Kl[(row * 128 + dc * 32 + lg * 8) ^ ((row & 7) << 3)]);
      s[kc] = __builtin_amdgcn_mfma_f32_16x16x32_bf16(aq[dc], bk, s[kc], 0, 0, 0);
    }
  }
#pragma unroll
  for (int i = 0; i < 4; ++i) {
    int qg = qbase + lg * 4 + i;
    float v[4];
#pragma unroll
    for (int kc = 0; kc < 4; ++kc) {
      v[kc] = s[kc][i] * scale;
      if (diag) {
        int kg = kb * 64 + kc * 16 + lr;
        if (kg > qg) v[kc] = -3.0e38f;
      }
    }
    float tm = fmaxf(fmaxf(v[0], v[1]), fmaxf(v[2], v[3]));
    tm = fmaxf(tm, __shfl_xor(tm, 1));
    tm = fmaxf(tm, __shfl_xor(tm, 2));
    tm = fmaxf(tm, __shfl_xor(tm, 4));
    tm = fmaxf(tm, __shfl_xor(tm, 8));
    float mn = fmaxf(m_r[i], tm);
    float alpha = __expf(m_r[i] - mn);
    float p[4], ts = 0.0f;
#pragma unroll
    for (int kc = 0; kc < 4; ++kc) { p[kc] = __expf(v[kc] - mn); ts += p[kc]; }
    ts += __shfl_xor(ts, 1);
    ts += __shfl_xor(ts, 2);
    ts += __shfl_xor(ts, 4);
    ts += __shfl_xor(ts, 8);
    l_r[i] = l_r[i] * alpha + ts;
    m_r[i] = mn;
#pragma unroll
    for (int t = 0; t < 8; ++t) oa[t][i] *= alpha;
    int row = lg * 4 + i;
#pragma unroll
    for (int kc = 0; kc < 4; ++kc)
      Plw[(row * 64 + kc * 16 + lr) ^ ((row & 7) << 3)] = f2b(p[kc]);
  }
  // wave-local LDS RAW fence (P written by all lanes of this wave, re-read below)
  asm volatile("s_waitcnt lgkmcnt(0)" ::: "memory");
#pragma unroll
  for (int kc = 0; kc < 2; ++kc) {
    bf16x8 ap = *reinterpret_cast<const bf16x8*>(
        &Plw[(lr * 64 + kc * 32 + lg * 8) ^ ((lr & 7) << 3)]);
#pragma unroll
    for (int t = 0; t < 8; ++t) {
      int dr = t * 16 + lr;
      bf16x8 bv = *reinterpret_cast<const bf16x8*>(
          &Vl[(dr * 64 + kc * 32 + lg * 8) ^ ((dr & 7) << 3)]);
      oa[t] = __builtin_amdgcn_mfma_f32_16x16x32_bf16(ap, bv, oa[t], 0, 0, 0);
    }
  }
}

__global__ __launch_bounds__(256, 2) void attn_kernel(const u16* __restrict__ Q,
                                                      const u16* __restrict__ K,
                                                      const u16* __restrict__ V,
                                                      u16* __restrict__ O) {
  __shared__ __align__(16) u16 Kl[64 * 128];      // swizzled [64 keys][128 d]
  __shared__ __align__(16) u16 Vl[128 * 64];      // swizzled [128 d][64 keys]
  __shared__ __align__(16) u16 Pl[2 * 4 * 16 * 64];  // per tile x wave [16 q][64 k]
  const int tid = threadIdx.x, lane = tid & 63, w = tid >> 6;
  const int lr = lane & 15, lg = lane >> 4;
  const int pi = blockIdx.x;  // 0..15
  const int ta = pi, tb = 31 - pi;
  const int b = blockIdx.y >> 4, h = blockIdx.y & 15, kv = h >> 2;
  const u16* Qp = Q + (size_t)(b * 16 + h) * 2048 * 128;
  const u16* Kp = K + (size_t)(b * 4 + kv) * 2048 * 128;
  const u16* Vp = V + (size_t)(b * 4 + kv) * 128 * 2048;
  const int qbA = ta * 64 + w * 16, qbB = tb * 64 + w * 16;
  bf16x8 aqA[4], aqB[4];
#pragma unroll
  for (int dc = 0; dc < 4; ++dc) {
    aqA[dc] = *reinterpret_cast<const bf16x8*>(Qp + (size_t)(qbA + lr) * 128 + dc * 32 + lg * 8);
    aqB[dc] = *reinterpret_cast<const bf16x8*>(Qp + (size_t)(qbB + lr) * 128 + dc * 32 + lg * 8);
  }
  float mA[4], lA[4], mB[4], lB[4];
  floatx4 oA[8] = {}, oB[8] = {};
#pragma unroll
  for (int i = 0; i < 4; ++i) { mA[i] = -3.0e38f; lA[i] = 0.0f; mB[i] = -3.0e38f; lB[i] = 0.0f; }
  u16* PlA = Pl + w * 1024;
  u16* PlB = Pl + 4096 + w * 1024;
  for (int kb = 0; kb <= tb; ++kb) {
    // stage K [64][128] and Vt [128][64] via global_load_lds, inverse-swizzled source
#pragma unroll
    for (int j = 0; j < 4; ++j) {
      int slot = w * 256 + j * 64 + lane;  // 16B slots
      int krow = slot >> 4, d16 = slot & 15;
      int dp = d16 ^ (krow & 7);
      gload_lds16(Kp + (size_t)(kb * 64 + krow) * 128 + dp * 8, &Kl[(w * 256 + j * 64) * 8]);
      int d = slot >> 3, k16 = slot & 7;
      int kp2 = k16 ^ (d & 7);
      gload_lds16(Vp + (size_t)d * 2048 + kb * 64 + kp2 * 8, &Vl[(w * 256 + j * 64) * 8]);
    }
    __syncthreads();
    if (kb <= ta) attn_tile(aqA, oA, mA, lA, PlA, Kl, Vl, qbA, kb, kb == ta, lr, lg);
    attn_tile(aqB, oB, mB, lB, PlB, Kl, Vl, qbB, kb, kb == tb, lr, lg);
    __syncthreads();
  }
#pragma unroll
  for (int i = 0; i < 4; ++i) {
    int sA = qbA + lg * 4 + i;
    int sB = qbB + lg * 4 + i;
    float invA = 1.0f / lA[i];
    float invB = 1.0f / lB[i];
#pragma unroll
    for (int t = 0; t < 8; ++t) {
      O[((size_t)b * 2048 + sA) * 2048 + h * 128 + t * 16 + lr] = f2b(oA[t][i] * invA);
      O[((size_t)b * 2048 + sB) * 2048 + h * 128 + t * 16 + lr] = f2b(oB[t][i] * invB);
    }
  }
}

extern "C" void kernel_launch(void* const* d_in, const int* in_sizes, int n_in,
                              void* d_out, int out_size, void* d_ws, size_t ws_size,
                              hipStream_t stream) {
  const float* x  = (const float*)d_in[0];
  const float* wq = (const float*)d_in[1];
  const float* wk = (const float*)d_in[2];
  const float* wv = (const float*)d_in[3];
  const float* wo = (const float*)d_in[4];
  float* out = (float*)d_out;
  char* ws = (char*)d_ws;
  size_t off = 0;
  auto alloc = [&](size_t bytes) -> void* {
    void* p = ws + off;
    off = (off + bytes + 255) & ~(size_t)255;
    return p;
  };
  u16* xb   = (u16*)alloc(4096ull * 2048 * 2);  // x bf16; later reused as q_rope
  u16* wqb  = (u16*)alloc(2048ull * 2048 * 2);
  u16* wkb  = (u16*)alloc(512ull * 2048 * 2);
  u16* wvb  = (u16*)alloc(512ull * 2048 * 2);
  u16* wob  = (u16*)alloc(2048ull * 2048 * 2);
  u16* qlin = (u16*)alloc(4096ull * 2048 * 2);  // later reused as attn output
  u16* klin = (u16*)alloc(4096ull * 512 * 2);
  u16* vlin = (u16*)alloc(4096ull * 512 * 2);
  u16* kr   = (u16*)alloc(4096ull * 512 * 2);
  u16* vtb  = (u16*)alloc(4096ull * 512 * 2);
  float* ctab = (float*)alloc(2048ull * 64 * 4);
  float* stab = (float*)alloc(2048ull * 64 * 4);
  u16* qr    = xb;    // safe: all projections read xb before rope_q runs
  u16* attnb = qlin;  // safe: qlin last read by rope_q, before attn runs
  (void)in_sizes; (void)n_in; (void)out_size; (void)ws_size;

  cvt_kernel<<<8192, 256, 0, stream>>>(x, xb, 2097152);
  cvt_kernel<<<4096, 256, 0, stream>>>(wq, wqb, 1048576);
  cvt_kernel<<<1024, 256, 0, stream>>>(wk, wkb, 262144);
  cvt_kernel<<<1024, 256, 0, stream>>>(wv, wvb, 262144);
  cvt_kernel<<<4096, 256, 0, stream>>>(wo, wob, 1048576);
  rope_table_kernel<<<512, 256, 0, stream>>>(ctab, stab);

  gemm_bt<u16><<<dim3(16, 32), 256, 0, stream>>>(xb, wqb, qlin, 4096, 2048, 2048);
  gemm_bt<u16><<<dim3(4, 32), 256, 0, stream>>>(xb, wkb, klin, 4096, 512, 2048);
  gemm_bt<u16><<<dim3(4, 32), 256, 0, stream>>>(xb, wvb, vlin, 4096, 512, 2048);

  rope_kernel<<<2048, 256, 0, stream>>>(qlin, qr, ctab, stab, 16);
  rope_kernel<<<512, 256, 0, stream>>>(klin, kr, ctab, stab, 4);
  vtrans_kernel<<<dim3(32, 8), 256, 0, stream>>>(vlin, vtb);

  attn_kernel<<<dim3(16, 32), 256, 0, stream>>>(qr, kr, vtb, attnb);

  gemm_bt<float><<<dim3(16, 32), 256, 0, stream>>>(attnb, wob, out, 4096, 2048, 2048);
}

// Round 3
// 286.474 us; speedup vs baseline: 1.6442x; 1.2933x over previous
//
#include <hip/hip_runtime.h>
#include <math.h>

typedef unsigned short u16;
typedef __attribute__((ext_vector_type(8))) short short8;
typedef __attribute__((ext_vector_type(8))) __bf16 bf16x8;
typedef __attribute__((ext_vector_type(4))) float floatx4;
typedef __attribute__((ext_vector_type(4))) unsigned short u16x4;
typedef __attribute__((ext_vector_type(4))) float float4v;

static __device__ __forceinline__ float b2f(u16 u) {
  unsigned int x = ((unsigned int)u) << 16;
  return __builtin_bit_cast(float, x);
}
static __device__ __forceinline__ u16 f2b(float f) {
  unsigned int x = __builtin_bit_cast(unsigned int, f);
  x += 0x7fffu + ((x >> 16) & 1u);
  return (u16)(x >> 16);
}
static __device__ __forceinline__ void gload_lds16(const void* g, void* l) {
  __builtin_amdgcn_global_load_lds(
      (const __attribute__((address_space(1))) unsigned int*)g,
      (__attribute__((address_space(3))) unsigned int*)l, 16, 0, 0);
}

// ---------- fused fp32 -> bf16 convert for all 5 inputs ----------
__global__ __launch_bounds__(256) void cvt5_kernel(
    const float* __restrict__ x, const float* __restrict__ wq,
    const float* __restrict__ wk, const float* __restrict__ wv,
    const float* __restrict__ wo, u16* __restrict__ xb, u16* __restrict__ wqb,
    u16* __restrict__ wkb, u16* __restrict__ wvb, u16* __restrict__ wob) {
  int bid = blockIdx.x;
  const float* in;
  u16* out;
  int i0;
  if (bid < 8192) { in = x; out = xb; i0 = bid; }
  else if (bid < 12288) { in = wq; out = wqb; i0 = bid - 8192; }
  else if (bid < 13312) { in = wk; out = wkb; i0 = bid - 12288; }
  else if (bid < 14336) { in = wv; out = wvb; i0 = bid - 13312; }
  else { in = wo; out = wob; i0 = bid - 14336; }
  int i = i0 * 256 + threadIdx.x;
  float4v v = reinterpret_cast<const float4v*>(in)[i];
  u16x4 o;
  o[0] = f2b(v[0]); o[1] = f2b(v[1]); o[2] = f2b(v[2]); o[3] = f2b(v[3]);
  reinterpret_cast<u16x4*>(out)[i] = o;
}

// ---------- RoPE cos/sin tables: [S=2048][64] fp32 ----------
__global__ __launch_bounds__(256) void rope_table_kernel(float* __restrict__ ct,
                                                         float* __restrict__ st) {
  int idx = blockIdx.x * 256 + threadIdx.x;  // S*64 = 131072
  int s = idx >> 6, j = idx & 63;
  float inv = powf(10000.0f, -(float)j * (1.0f / 64.0f));
  float ang = (float)s * inv;
  ct[idx] = cosf(ang);
  st[idx] = sinf(ang);
}

// ---------- RoPE for K: qkv[bs][2048 + h*128 + d] -> [B][4][S][128] ----------
__global__ __launch_bounds__(256) void rope_k_kernel(const u16* __restrict__ in,
                                                     u16* __restrict__ out,
                                                     const float* __restrict__ ct,
                                                     const float* __restrict__ st) {
  int idx = blockIdx.x * 256 + threadIdx.x;  // B*S*4*8 = 131072
  int jc = idx & 7;
  int rest = idx >> 3;
  int h = rest & 3;
  int bs = rest >> 2;
  int s = bs & 2047;
  int b = bs >> 11;
  int j0 = jc * 8;
  size_t inoff = (size_t)bs * 3072 + 2048 + h * 128 + j0;
  short8 lo = *reinterpret_cast<const short8*>(&in[inoff]);
  short8 hi = *reinterpret_cast<const short8*>(&in[inoff + 64]);
  short8 o0, o1;
#pragma unroll
  for (int e = 0; e < 8; ++e) {
    float c = ct[s * 64 + j0 + e], sn = st[s * 64 + j0 + e];
    float t1 = b2f((u16)lo[e]);
    float t2 = b2f((u16)hi[e]);
    o0[e] = (short)f2b(t1 * c - t2 * sn);
    o1[e] = (short)f2b(t2 * c + t1 * sn);
  }
  size_t ooff = ((size_t)(b * 4 + h) * 2048 + s) * 128 + j0;
  *reinterpret_cast<short8*>(&out[ooff]) = o0;
  *reinterpret_cast<short8*>(&out[ooff + 64]) = o1;
}

// ---------- V transpose: qkv[bs][2560 + kv*128 + d] -> [B][KV][128][S] ----------
__global__ __launch_bounds__(256) void vtrans_kernel(const u16* __restrict__ in,
                                                     u16* __restrict__ out) {
  __shared__ u16 t[128][66];
  int s0 = blockIdx.x * 64;
  int b = blockIdx.y >> 2, kv = blockIdx.y & 3;
  int tid = threadIdx.x;
#pragma unroll
  for (int it = 0; it < 32; ++it) {
    int idx = it * 256 + tid;
    int sl = idx >> 7, d = idx & 127;
    t[d][sl] = in[(size_t)(b * 2048 + s0 + sl) * 3072 + 2560 + kv * 128 + d];
  }
  __syncthreads();
#pragma unroll
  for (int it = 0; it < 32; ++it) {
    int idx = it * 256 + tid;
    int d = idx >> 6, sl = idx & 63;
    out[(size_t)((b * 4 + kv) * 128 + d) * 2048 + s0 + sl] = t[d][sl];
  }
}

// ---------- bf16 GEMM: C[M][N] = A[M][K] * B[N][K]^T (m97-style 128x128 tile) ----------
static __device__ __forceinline__ void store_out(u16* p, float v) { *p = f2b(v); }
static __device__ __forceinline__ void store_out(float* p, float v) { *p = v; }

template <typename OutT>
__global__ __launch_bounds__(256) void gemm_bt(const u16* __restrict__ A,
                                               const u16* __restrict__ B,
                                               OutT* __restrict__ C, int M, int N, int K) {
  __shared__ __align__(16) u16 Al[128 * 32];
  __shared__ __align__(16) u16 Bl[128 * 32];
  const int tid = threadIdx.x;
  const int lane = tid & 63;
  const int w = tid >> 6;
  const int wr = w >> 1, wc = w & 1;
  const int lr = lane & 15, lg = lane >> 4;
  const int brow = blockIdx.y, bcol = blockIdx.x;
  const int r0 = lane >> 2, kp = lane & 3;
  const u16* Ag = A + (size_t)(brow * 128) * K;
  const u16* Bg = B + (size_t)(bcol * 128) * K;
  floatx4 acc[4][4] = {};
  for (int k0 = 0; k0 < K; k0 += 32) {
#pragma unroll
    for (int j = 0; j < 2; ++j) {
      int c = w * 2 + j;
      int row = c * 16 + r0;
      gload_lds16(Ag + (size_t)row * K + k0 + kp * 8, &Al[c * 512]);
      gload_lds16(Bg + (size_t)row * K + k0 + kp * 8, &Bl[c * 512]);
    }
    __syncthreads();
    bf16x8 af[4], bfr[4];
#pragma unroll
    for (int m = 0; m < 4; ++m)
      af[m] = *reinterpret_cast<const bf16x8*>(&Al[(wr * 64 + m * 16 + lr) * 32 + lg * 8]);
#pragma unroll
    for (int n = 0; n < 4; ++n)
      bfr[n] = *reinterpret_cast<const bf16x8*>(&Bl[(wc * 64 + n * 16 + lr) * 32 + lg * 8]);
#pragma unroll
    for (int m = 0; m < 4; ++m)
#pragma unroll
      for (int n = 0; n < 4; ++n)
        acc[m][n] = __builtin_amdgcn_mfma_f32_16x16x32_bf16(af[m], bfr[n], acc[m][n], 0, 0, 0);
    __syncthreads();
  }
#pragma unroll
  for (int m = 0; m < 4; ++m) {
    int row = brow * 128 + wr * 64 + m * 16 + lg * 4;
#pragma unroll
    for (int n = 0; n < 4; ++n) {
      int col = bcol * 128 + wc * 64 + n * 16 + lr;
#pragma unroll
      for (int i = 0; i < 4; ++i) store_out(&C[(size_t)(row + i) * N + col], acc[m][n][i]);
    }
  }
}

// ---------- causal GQA flash attention, v3 ----------
// Paired q-tiles, KVBLK=64, double-buffered K/V staging (issue-early),
// defer-max rescale (THR=8), setprio around MFMA clusters, fused Q-RoPE.
static __device__ __forceinline__ void attn_tile(
    const bf16x8 (&aq)[4], floatx4 (&oa)[8], float (&m_r)[4], float (&l_r)[4],
    u16* __restrict__ Plw, const u16* __restrict__ Kl, const u16* __restrict__ Vl,
    int qbase, int kb, bool diag, int lr, int lg) {
  const float scale = 0.08838834764831845f;
  floatx4 s[4] = {};
  __builtin_amdgcn_s_setprio(1);
#pragma unroll
  for (int dc = 0; dc < 4; ++dc) {
#pragma unroll
    for (int kc = 0; kc < 4; ++kc) {
      int row = kc * 16 + lr;
      bf16x8 bk = *reinterpret_cast<const bf16x8*>(
          &Kl[(row * 128 + dc * 32 + lg * 8) ^ ((row & 7) << 3)]);
      s[kc] = __builtin_amdgcn_mfma_f32_16x16x32_bf16(aq[dc], bk, s[kc], 0, 0, 0);
    }
  }
  __builtin_amdgcn_s_setprio(0);
  float v[4][4], tm4[4];
#pragma unroll
  for (int i = 0; i < 4; ++i) {
    int qg = qbase + lg * 4 + i;
#pragma unroll
    for (int kc = 0; kc < 4; ++kc) {
      v[i][kc] = s[kc][i] * scale;
      if (diag && (kb * 64 + kc * 16 + lr > qg)) v[i][kc] = -3.0e38f;
    }
    float tm = fmaxf(fmaxf(v[i][0], v[i][1]), fmaxf(v[i][2], v[i][3]));
    tm = fmaxf(tm, __shfl_xor(tm, 1));
    tm = fmaxf(tm, __shfl_xor(tm, 2));
    tm = fmaxf(tm, __shfl_xor(tm, 4));
    tm = fmaxf(tm, __shfl_xor(tm, 8));
    tm4[i] = tm;
  }
  // defer-max: only rescale when some row's max grew by > 8
  float need = fmaxf(fmaxf(tm4[0] - m_r[0], tm4[1] - m_r[1]),
                     fmaxf(tm4[2] - m_r[2], tm4[3] - m_r[3]));
  if (!__all(need <= 8.0f)) {
#pragma unroll
    for (int i = 0; i < 4; ++i) {
      float mn = fmaxf(m_r[i], tm4[i]);
      float alpha = __expf(m_r[i] - mn);
      m_r[i] = mn;
      l_r[i] *= alpha;
#pragma unroll
      for (int t = 0; t < 8; ++t) oa[t][i] *= alpha;
    }
  }
#pragma unroll
  for (int i = 0; i < 4; ++i) {
    int row = lg * 4 + i;
    float ts = 0.0f;
#pragma unroll
    for (int kc = 0; kc < 4; ++kc) {
      float p = __expf(v[i][kc] - m_r[i]);
      ts += p;
      Plw[(row * 64 + kc * 16 + lr) ^ ((row & 7) << 3)] = f2b(p);
    }
    ts += __shfl_xor(ts, 1);
    ts += __shfl_xor(ts, 2);
    ts += __shfl_xor(ts, 4);
    ts += __shfl_xor(ts, 8);
    l_r[i] += ts;
  }
  // wave-local LDS RAW fence (P written by all lanes of this wave, re-read below)
  asm volatile("s_waitcnt lgkmcnt(0)" ::: "memory");
  __builtin_amdgcn_s_setprio(1);
#pragma unroll
  for (int kc = 0; kc < 2; ++kc) {
    bf16x8 ap = *reinterpret_cast<const bf16x8*>(
        &Plw[(lr * 64 + kc * 32 + lg * 8) ^ ((lr & 7) << 3)]);
#pragma unroll
    for (int t = 0; t < 8; ++t) {
      int dr = t * 16 + lr;
      bf16x8 bv = *reinterpret_cast<const bf16x8*>(
          &Vl[(dr * 64 + kc * 32 + lg * 8) ^ ((dr & 7) << 3)]);
      oa[t] = __builtin_amdgcn_mfma_f32_16x16x32_bf16(ap, bv, oa[t], 0, 0, 0);
    }
  }
  __builtin_amdgcn_s_setprio(0);
}

__global__ __launch_bounds__(256, 2) void attn_kernel(const u16* __restrict__ QKV,
                                                      const u16* __restrict__ K,
                                                      const u16* __restrict__ V,
                                                      const float* __restrict__ ct,
                                                      const float* __restrict__ st,
                                                      u16* __restrict__ O) {
  __shared__ __align__(16) u16 Kl[2][64 * 128];   // swizzled, double-buffered
  __shared__ __align__(16) u16 Vl[2][128 * 64];
  __shared__ __align__(16) u16 Pl[2 * 4 * 16 * 64];
  const int tid = threadIdx.x, lane = tid & 63, w = tid >> 6;
  const int lr = lane & 15, lg = lane >> 4;
  const int pi = blockIdx.x;  // 0..15
  const int ta = pi, tb = 31 - pi;
  const int b = blockIdx.y >> 4, h = blockIdx.y & 15, kv = h >> 2;
  const u16* Kp = K + (size_t)(b * 4 + kv) * 2048 * 128;
  const u16* Vp = V + (size_t)(b * 4 + kv) * 128 * 2048;
  const int qbA = ta * 64 + w * 16, qbB = tb * 64 + w * 16;

  // load Q from qkv-linear layout and apply RoPE in-register
  bf16x8 aqA[4], aqB[4];
  auto load_q = [&](int qb, bf16x8(&aq)[4]) {
    int srow = qb + lr;
    const u16* qp = QKV + (size_t)(b * 2048 + srow) * 3072 + h * 128;
    short8 r[4];
#pragma unroll
    for (int dc = 0; dc < 4; ++dc)
      r[dc] = *reinterpret_cast<const short8*>(qp + dc * 32 + lg * 8);
    const float* cb = ct + srow * 64;
    const float* sb = st + srow * 64;
#pragma unroll
    for (int dc = 0; dc < 2; ++dc) {
      short8 olo, ohi;
#pragma unroll
      for (int e = 0; e < 8; ++e) {
        int j = dc * 32 + lg * 8 + e;
        float c = cb[j], sn = sb[j];
        float t1 = b2f((u16)r[dc][e]);
        float t2 = b2f((u16)r[dc + 2][e]);
        olo[e] = (short)f2b(t1 * c - t2 * sn);
        ohi[e] = (short)f2b(t2 * c + t1 * sn);
      }
      aq[dc] = __builtin_bit_cast(bf16x8, olo);
      aq[dc + 2] = __builtin_bit_cast(bf16x8, ohi);
    }
  };
  load_q(qbA, aqA);
  load_q(qbB, aqB);

  float mA[4], lA[4], mB[4], lB[4];
  floatx4 oA[8] = {}, oB[8] = {};
#pragma unroll
  for (int i = 0; i < 4; ++i) { mA[i] = -3.0e38f; lA[i] = 0.0f; mB[i] = -3.0e38f; lB[i] = 0.0f; }
  u16* PlA = Pl + w * 1024;
  u16* PlB = Pl + 4096 + w * 1024;

  auto stage = [&](int buf, int kb) {
#pragma unroll
    for (int j = 0; j < 4; ++j) {
      int slot = w * 256 + j * 64 + lane;  // 16B slots
      int krow = slot >> 4, d16 = slot & 15;
      int dp = d16 ^ (krow & 7);
      gload_lds16(Kp + (size_t)(kb * 64 + krow) * 128 + dp * 8,
                  &Kl[buf][(w * 256 + j * 64) * 8]);
      int d = slot >> 3, k16 = slot & 7;
      int kp2 = k16 ^ (d & 7);
      gload_lds16(Vp + (size_t)d * 2048 + kb * 64 + kp2 * 8,
                  &Vl[buf][(w * 256 + j * 64) * 8]);
    }
  };

  stage(0, 0);
  __syncthreads();
  int cur = 0;
  for (int kb = 0; kb <= tb; ++kb) {
    if (kb < tb) stage(cur ^ 1, kb + 1);  // issue-early: overlaps with compute below
    if (kb <= ta) attn_tile(aqA, oA, mA, lA, PlA, Kl[cur], Vl[cur], qbA, kb, kb == ta, lr, lg);
    attn_tile(aqB, oB, mB, lB, PlB, Kl[cur], Vl[cur], qbB, kb, kb == tb, lr, lg);
    __syncthreads();  // drains this iteration's stage loads (hidden under compute)
    cur ^= 1;
  }
#pragma unroll
  for (int i = 0; i < 4; ++i) {
    int sA = qbA + lg * 4 + i;
    int sB = qbB + lg * 4 + i;
    float invA = 1.0f / lA[i];
    float invB = 1.0f / lB[i];
#pragma unroll
    for (int t = 0; t < 8; ++t) {
      O[((size_t)b * 2048 + sA) * 2048 + h * 128 + t * 16 + lr] = f2b(oA[t][i] * invA);
      O[((size_t)b * 2048 + sB) * 2048 + h * 128 + t * 16 + lr] = f2b(oB[t][i] * invB);
    }
  }
}

extern "C" void kernel_launch(void* const* d_in, const int* in_sizes, int n_in,
                              void* d_out, int out_size, void* d_ws, size_t ws_size,
                              hipStream_t stream) {
  const float* x  = (const float*)d_in[0];
  const float* wq = (const float*)d_in[1];
  const float* wk = (const float*)d_in[2];
  const float* wv = (const float*)d_in[3];
  const float* wo = (const float*)d_in[4];
  float* out = (float*)d_out;
  char* ws = (char*)d_ws;
  size_t off = 0;
  auto alloc = [&](size_t bytes) -> void* {
    void* p = ws + off;
    off = (off + bytes + 255) & ~(size_t)255;
    return p;
  };
  u16* xb   = (u16*)alloc(4096ull * 2048 * 2);  // x bf16; reused as attn output
  u16* wqb  = (u16*)alloc(2048ull * 2048 * 2);  // wqb/wkb/wvb contiguous = [3072][2048]
  u16* wkb  = (u16*)alloc(512ull * 2048 * 2);
  u16* wvb  = (u16*)alloc(512ull * 2048 * 2);
  u16* wob  = (u16*)alloc(2048ull * 2048 * 2);
  u16* qkv  = (u16*)alloc(4096ull * 3072 * 2);  // [B*S][3072] = q | k | v
  u16* kr   = (u16*)alloc(4096ull * 512 * 2);   // [B][4][S][128]
  u16* vtb  = (u16*)alloc(4096ull * 512 * 2);   // [B][4][128][S]
  float* ctab = (float*)alloc(2048ull * 64 * 4);
  float* stab = (float*)alloc(2048ull * 64 * 4);
  u16* attnb = xb;  // safe: xb last read by gemm_qkv, attn runs after
  (void)in_sizes; (void)n_in; (void)out_size; (void)ws_size;

  cvt5_kernel<<<18432, 256, 0, stream>>>(x, wq, wk, wv, wo, xb, wqb, wkb, wvb, wob);
  rope_table_kernel<<<512, 256, 0, stream>>>(ctab, stab);

  // fused q|k|v projection: [4096][2048] x [3072][2048]^T
  gemm_bt<u16><<<dim3(24, 32), 256, 0, stream>>>(xb, wqb, qkv, 4096, 3072, 2048);

  rope_k_kernel<<<512, 256, 0, stream>>>(qkv, kr, ctab, stab);
  vtrans_kernel<<<dim3(32, 8), 256, 0, stream>>>(qkv, vtb);

  attn_kernel<<<dim3(16, 32), 256, 0, stream>>>(qkv, kr, vtb, ctab, stab, attnb);

  gemm_bt<float><<<dim3(16, 32), 256, 0, stream>>>(attnb, wob, out, 4096, 2048, 2048);
}